// Round 1
// baseline (1012.948 us; speedup 1.0000x reference)
//
#include <hip/hip_runtime.h>

#define N 65536
#define D 64
#define V 8192
#define BM 128
#define BN 128
#define NCHUNK (V / BN)       // 64
#define LOSS_OFF (N * D)      // 4194304
#define IDX_OFF (N * D + 1)   // 4194305

// LDS layout: [k][r] stride 128, XOR swizzle of r-bits 2..4 with k-bits 0..2.
// - b128 reads at r%4==0 stay contiguous & 16B-aligned (XOR only touches bits>=2)
// - read at fixed k: distinct r -> distinct banks (conflict-free / 2-way free)
// - scatter-writes during staging: ~4-8 way conflict but staging is <1% of work
__device__ __forceinline__ int swz(int k, int r) {
    return k * 128 + (r ^ ((k & 7) << 2));
}

// ---------------- kernel 1: e2[v] = sum_d E[v][d]^2 ; zero loss slot --------
__global__ void k_e2(const float* __restrict__ E, float* __restrict__ e2,
                     float* __restrict__ dout) {
    int v = blockIdx.x * blockDim.x + threadIdx.x;
    if (v == 0) dout[LOSS_OFF] = 0.0f;
    if (v < V) {
        const float4* row = (const float4*)(E + (size_t)v * D);
        float s = 0.0f;
#pragma unroll
        for (int i = 0; i < 16; ++i) {
            float4 t = row[i];
            s += t.x * t.x + t.y * t.y + t.z * t.z + t.w * t.w;
        }
        e2[v] = s;
    }
}

// ---------------- kernel 2: fused distance + argmin -------------------------
__global__ __launch_bounds__(256) void k_argmin(const float* __restrict__ X,
                                                const float* __restrict__ E,
                                                const float* __restrict__ e2,
                                                float* __restrict__ dout) {
    __shared__ __align__(16) float xs[64 * 128];  // 32 KB, [k][r] swizzled
    __shared__ __align__(16) float es[64 * 128];  // 32 KB, [k][c] swizzled

    const int t = threadIdx.x;
    const int tx = t & 15;        // column group (entries)
    const int ty = t >> 4;        // row group (x rows)
    const int kq = tx * 4;        // k-quad this thread stages
    const int rbase = blockIdx.x * BM;

    // stage x tile (once): thread loads rows ty*8+i at k-quad kq (coalesced
    // 16 lanes x 16B = 256B runs), scatter-write transposed into LDS.
    {
        const int r0 = ty * 8;
#pragma unroll
        for (int i = 0; i < 8; ++i) {
            float4 vx = *(const float4*)(X + (size_t)(rbase + r0 + i) * D + kq);
            xs[swz(kq + 0, r0 + i)] = vx.x;
            xs[swz(kq + 1, r0 + i)] = vx.y;
            xs[swz(kq + 2, r0 + i)] = vx.z;
            xs[swz(kq + 3, r0 + i)] = vx.w;
        }
    }

    float vmin[8];
    int vidx[8];
#pragma unroll
    for (int i = 0; i < 8; ++i) {
        vmin[i] = 3.4e38f;
        vidx[i] = 0;
    }

    for (int ch = 0; ch < NCHUNK; ++ch) {
        const int cbase = ch * BN;
        __syncthreads();  // previous chunk's readers done before overwrite
        {
            const int c0 = ty * 8;
#pragma unroll
            for (int i = 0; i < 8; ++i) {
                float4 ve =
                    *(const float4*)(E + (size_t)(cbase + c0 + i) * D + kq);
                es[swz(kq + 0, c0 + i)] = ve.x;
                es[swz(kq + 1, c0 + i)] = ve.y;
                es[swz(kq + 2, c0 + i)] = ve.z;
                es[swz(kq + 3, c0 + i)] = ve.w;
            }
        }
        __syncthreads();

        float acc[8][8];
#pragma unroll
        for (int i = 0; i < 8; ++i)
#pragma unroll
            for (int j = 0; j < 8; ++j) acc[i][j] = 0.0f;

#pragma unroll 4
        for (int k = 0; k < 64; ++k) {
            float a[8], b[8];
            *(float4*)&a[0] = *(const float4*)&xs[swz(k, ty * 8)];
            *(float4*)&a[4] = *(const float4*)&xs[swz(k, ty * 8 + 4)];
            *(float4*)&b[0] = *(const float4*)&es[swz(k, tx * 8)];
            *(float4*)&b[4] = *(const float4*)&es[swz(k, tx * 8 + 4)];
#pragma unroll
            for (int i = 0; i < 8; ++i)
#pragma unroll
                for (int j = 0; j < 8; ++j) acc[i][j] += a[i] * b[j];
        }

        // d2 = e2[c] - 2*dot  (x^2 omitted: constant per row, argmin-invariant)
        float e2v[8];
        *(float4*)&e2v[0] = *(const float4*)&e2[cbase + tx * 8];
        *(float4*)&e2v[4] = *(const float4*)&e2[cbase + tx * 8 + 4];
#pragma unroll
        for (int i = 0; i < 8; ++i) {
#pragma unroll
            for (int j = 0; j < 8; ++j) {
                float d = fmaf(-2.0f, acc[i][j], e2v[j]);
                int c = cbase + tx * 8 + j;
                if (d < vmin[i]) {  // strict < keeps lowest index on ties
                    vmin[i] = d;
                    vidx[i] = c;
                }
            }
        }
    }

    // reduce across the 16 column-threads sharing each row (lanes differ in
    // bits 0..3 -> width-16 XOR butterfly stays in-wave)
#pragma unroll
    for (int i = 0; i < 8; ++i) {
        float v = vmin[i];
        int id = vidx[i];
        for (int off = 8; off; off >>= 1) {
            float ov = __shfl_xor(v, off, 16);
            int oid = __shfl_xor(id, off, 16);
            if (ov < v || (ov == v && oid < id)) {
                v = ov;
                id = oid;
            }
        }
        if (tx == 0) dout[IDX_OFF + rbase + ty * 8 + i] = (float)id;
    }
}

// ---------------- kernel 3: gather + STE output + loss ----------------------
__global__ void k_out(const float* __restrict__ X, const float* __restrict__ E,
                      float* __restrict__ dout) {
    const int t = blockIdx.x * 256 + threadIdx.x;
    const int n = t >> 4;
    const int d = (t & 15) * 4;
    const int idx = (int)dout[IDX_OFF + n];
    float4 x4 = *(const float4*)(X + (size_t)n * D + d);
    float4 q4 = *(const float4*)(E + (size_t)idx * D + d);
    float4 o;
    o.x = x4.x + (q4.x - x4.x);
    o.y = x4.y + (q4.y - x4.y);
    o.z = x4.z + (q4.z - x4.z);
    o.w = x4.w + (q4.w - x4.w);
    *(float4*)(dout + (size_t)n * D + d) = o;

    float dx = q4.x - x4.x, dy = q4.y - x4.y, dz = q4.z - x4.z,
          dw = q4.w - x4.w;
    float s = dx * dx + dy * dy + dz * dz + dw * dw;
#pragma unroll
    for (int off = 32; off; off >>= 1) s += __shfl_down(s, off, 64);
    __shared__ float ps[4];
    if ((threadIdx.x & 63) == 0) ps[threadIdx.x >> 6] = s;
    __syncthreads();
    if (threadIdx.x == 0) {
        float tot = ps[0] + ps[1] + ps[2] + ps[3];
        atomicAdd(dout + LOSS_OFF, tot * (1.25f / ((float)N * (float)D)));
    }
}

extern "C" void kernel_launch(void* const* d_in, const int* in_sizes, int n_in,
                              void* d_out, int out_size, void* d_ws,
                              size_t ws_size, hipStream_t stream) {
    const float* X = (const float*)d_in[0];
    const float* E = (const float*)d_in[1];
    float* out = (float*)d_out;
    float* e2 = (float*)d_ws;  // 8192 floats = 32 KB scratch

    k_e2<<<(V + 255) / 256, 256, 0, stream>>>(E, e2, out);
    k_argmin<<<N / BM, 256, 0, stream>>>(X, E, e2, out);
    k_out<<<(N * 16) / 256, 256, 0, stream>>>(X, E, out);
}